// Round 6
// baseline (472.986 us; speedup 1.0000x reference)
//
#include <hip/hip_runtime.h>
#include <cstdint>

// ---------------------------------------------------------------------------
// InvariantPointAttention fused kernel set for MI355X (gfx950)
// N=768, C_S=384, C_Z=128, C_IPA=16, H=12, NQ=4, NV=8
// ---------------------------------------------------------------------------

typedef __attribute__((ext_vector_type(8))) short short8;
typedef __attribute__((ext_vector_type(4))) short short4_t;
typedef __attribute__((ext_vector_type(4))) float f32x4;

__device__ __forceinline__ unsigned short f2bf(float f) {
    unsigned u = __float_as_uint(f);
    u = (u + 0x7FFFu + ((u >> 16) & 1u)) >> 16;   // RNE
    return (unsigned short)u;
}
__device__ __forceinline__ float bf2f(unsigned short s) {
    return __uint_as_float(((unsigned)s) << 16);
}
__device__ __forceinline__ unsigned pk2(float lo, float hi) {
    return (unsigned)f2bf(lo) | ((unsigned)f2bf(hi) << 16);
}
// subtile placement offset: H[g] = {0,6,20,26}; 44*H[g] mod 32 = {0,8,16,24}
__device__ __forceinline__ int HOFF(int gg) {
    return gg * 6 + ((gg & 2) << 2);
}

#define NS_QK  0.14433756729740643f   // sqrt(1/48)
#define NS_B   0.5773502691896258f    // sqrt(1/3)
#define NS_HW  0.13608276348795434f   // sqrt(1/54)

// ---------------------------------------------------------------------------
// Kernel 1: fused projection GEMM.  s (768x384) @ [Wq|Wkv|Wq3|Wkv3] (384x1152)
// Outputs: Qw f32[768][192], Kw bf16[768][12][16], Vt bf16[192][768] (transposed),
//          P3q f32, P3kv f32 (pre-rotation)
// ---------------------------------------------------------------------------
__global__ __launch_bounds__(256) void proj_kernel(
    const float* __restrict__ s,
    const float* __restrict__ Wq,   const float* __restrict__ bq,
    const float* __restrict__ Wkv,  const float* __restrict__ bkv,
    const float* __restrict__ Wq3,  const float* __restrict__ bq3,
    const float* __restrict__ Wkv3, const float* __restrict__ bkv3,
    float* __restrict__ Qw, unsigned short* __restrict__ Kw,
    unsigned short* __restrict__ Vt,
    float* __restrict__ P3q, float* __restrict__ P3kv)
{
    __shared__ __align__(16) float s_lds[32 * 384];
    const int t  = threadIdx.x;
    const int r0 = blockIdx.x * 32;
    const int c0 = blockIdx.y * 128;

    for (int u = t; u < 3072; u += 256) {
        int r = u / 96, c4 = u - r * 96;
        *(float4*)&s_lds[r * 384 + c4 * 4] =
            *(const float4*)&s[(size_t)(r0 + r) * 384 + c4 * 4];
    }
    __syncthreads();

    const int rg = t >> 6;
    const int lc = t & 63;
    const int colA = c0 + lc;
    const int colB = c0 + lc + 64;

    const float *wpA, *wpB; int ldA, ldB; float biasA, biasB;
    {
        int col = colA;
        if (col < 192)      { wpA = Wq   + col;       ldA = 192; biasA = bq[col]; }
        else if (col < 576) { wpA = Wkv  + (col-192); ldA = 384; biasA = bkv[col-192]; }
        else if (col < 720) { wpA = Wq3  + (col-576); ldA = 144; biasA = bq3[col-576]; }
        else                { wpA = Wkv3 + (col-720); ldA = 432; biasA = bkv3[col-720]; }
        col = colB;
        if (col < 192)      { wpB = Wq   + col;       ldB = 192; biasB = bq[col]; }
        else if (col < 576) { wpB = Wkv  + (col-192); ldB = 384; biasB = bkv[col-192]; }
        else if (col < 720) { wpB = Wq3  + (col-576); ldB = 144; biasB = bq3[col-576]; }
        else                { wpB = Wkv3 + (col-720); ldB = 432; biasB = bkv3[col-720]; }
    }

    float acc0[8] = {}, acc1[8] = {};
    for (int k = 0; k < 384; k += 4) {
        float4 sv[8];
        #pragma unroll
        for (int r = 0; r < 8; r++)
            sv[r] = *(const float4*)&s_lds[(rg*8 + r) * 384 + k];
        #pragma unroll
        for (int kk = 0; kk < 4; kk++) {
            float w0 = wpA[(k + kk) * ldA];
            float w1 = wpB[(k + kk) * ldB];
            #pragma unroll
            for (int r = 0; r < 8; r++) {
                float sval = ((const float*)&sv[r])[kk];
                acc0[r] += sval * w0;
                acc1[r] += sval * w1;
            }
        }
    }

    #pragma unroll
    for (int q = 0; q < 2; q++) {
        int col   = q ? colB : colA;
        float bia = q ? biasB : biasA;
        #pragma unroll
        for (int r = 0; r < 8; r++) {
            int row = r0 + rg*8 + r;
            float v = (q ? acc1[r] : acc0[r]) + bia;
            if (col < 192) {
                Qw[(size_t)row*192 + col] = v;
            } else if (col < 576) {
                int c = col - 192, h = c >> 5, sub = c & 31;
                if (sub < 16) Kw[(size_t)row*192 + h*16 + sub] = f2bf(v);
                else          Vt[(size_t)(h*16 + (sub-16))*768 + row] = f2bf(v);
            } else if (col < 720) {
                P3q[(size_t)row*144 + (col-576)] = v;
            } else {
                P3kv[(size_t)row*432 + (col-720)] = v;
            }
        }
    }
}

// ---------------------------------------------------------------------------
// Kernel 2: rotate/translate projected points.
// Q3w f32[768][h*12+q*3+d], K3w f32[768][h*12+q*3+d], V3t bf16[288][768]
// ---------------------------------------------------------------------------
__global__ __launch_bounds__(192) void rot3_kernel(
    const float* __restrict__ P3q, const float* __restrict__ P3kv,
    const float* __restrict__ rots, const float* __restrict__ trans,
    float* __restrict__ Q3w, float* __restrict__ K3w,
    unsigned short* __restrict__ V3t)
{
    const int n = blockIdx.x;
    const int t = threadIdx.x;
    float R[9];
    #pragma unroll
    for (int u = 0; u < 9; u++) R[u] = rots[n*9 + u];
    float T0 = trans[n*3+0], T1 = trans[n*3+1], T2 = trans[n*3+2];

    float p0, p1, p2;
    if (t < 48) {
        p0 = P3q[(size_t)n*144 + t];
        p1 = P3q[(size_t)n*144 + 48 + t];
        p2 = P3q[(size_t)n*144 + 96 + t];
    } else {
        int k = t - 48;
        p0 = P3kv[(size_t)n*432 + k];
        p1 = P3kv[(size_t)n*432 + 144 + k];
        p2 = P3kv[(size_t)n*432 + 288 + k];
    }
    float o0 = R[0]*p0 + R[1]*p1 + R[2]*p2 + T0;
    float o1 = R[3]*p0 + R[4]*p1 + R[5]*p2 + T1;
    float o2 = R[6]*p0 + R[7]*p1 + R[8]*p2 + T2;

    if (t < 48) {
        Q3w[(size_t)n*144 + t*3 + 0] = o0;
        Q3w[(size_t)n*144 + t*3 + 1] = o1;
        Q3w[(size_t)n*144 + t*3 + 2] = o2;
    } else {
        int k = t - 48, h = k / 12, m = k % 12;
        if (m < 4) {
            size_t base = (size_t)n*144 + (h*4 + m)*3;
            K3w[base+0] = o0; K3w[base+1] = o1; K3w[base+2] = o2;
        } else {
            int rv = (h*8 + (m-4))*3;
            V3t[(size_t)(rv+0)*768 + n] = f2bf(o0);
            V3t[(size_t)(rv+1)*768 + n] = f2bf(o1);
            V3t[(size_t)(rv+2)*768 + n] = f2bf(o2);
        }
    }
}

// ---------------------------------------------------------------------------
// Kernel 2b: build extended logit vectors.
//   EK[j][h][32] = [K(16) | K3(12) | bb*nsB-0.5hw*kn | 1 | m_j*S | -S]
//   EQ[i][h][32] = [Q*ns(16) | Q3*hw(12) | 1 | -0.5hw*qn | m_i*S | +S]
//   dot(EQ,EK) = ns*qk + hw*cross - 0.5hw(qn+kn) + bb*nsB + (mi*mj-1)*S^2
// NOTE: cols 30/31 must be accumulated as an ISOLATED pair (exact cancel).
// grid 192, block 256 (4 idx per block, lane h = t&63)
// ---------------------------------------------------------------------------
__global__ __launch_bounds__(256) void ek_kernel(
    const float* __restrict__ Qw, const unsigned short* __restrict__ Kw,
    const float* __restrict__ Q3w, const float* __restrict__ K3w,
    const float* __restrict__ mask, const float* __restrict__ hw,
    const float* __restrict__ bb,
    unsigned short* __restrict__ EQw, unsigned short* __restrict__ EKw)
{
    const int idx = blockIdx.x * 4 + (threadIdx.x >> 6);
    const int h   = threadIdx.x & 63;
    if (h >= 12) return;
    const float hws = log1pf(__expf(hw[h])) * NS_HW;
    const float mi  = mask[idx];
    const float S   = 31616.0f;   // bf16-exact; S^2 = 2^14 * 61009 exact in f32

    unsigned short row[32];
    // EK
    {
        const unsigned short* kp = Kw + (size_t)idx*192 + h*16;
        #pragma unroll
        for (int c = 0; c < 16; c++) row[c] = kp[c];
        const float* k3 = K3w + (size_t)idx*144 + h*12;
        float kn = 0.0f;
        #pragma unroll
        for (int e = 0; e < 12; e++) {
            unsigned short b = f2bf(k3[e]);
            row[16+e] = b;
            float f = bf2f(b); kn += f*f;
        }
        row[28] = f2bf(bb[h]*NS_B - 0.5f*hws*kn);
        row[29] = f2bf(1.0f);
        row[30] = f2bf(mi * S);
        row[31] = f2bf(-S);
        unsigned short* o = EKw + ((size_t)idx*12 + h)*32;
        #pragma unroll
        for (int c = 0; c < 32; c++) o[c] = row[c];
    }
    // EQ
    {
        const float* qp = Qw + (size_t)idx*192 + h*16;
        #pragma unroll
        for (int c = 0; c < 16; c++) row[c] = f2bf(qp[c] * NS_QK);
        const float* q3 = Q3w + (size_t)idx*144 + h*12;
        float qn = 0.0f;
        #pragma unroll
        for (int e = 0; e < 12; e++) {
            float f = q3[e];
            row[16+e] = f2bf(f * hws);
            qn += f*f;
        }
        row[28] = f2bf(1.0f);
        row[29] = f2bf(-0.5f*hws*qn);
        row[30] = f2bf(mi * S);
        row[31] = f2bf(S);
        unsigned short* o = EQw + ((size_t)idx*12 + h)*32;
        #pragma unroll
        for (int c = 0; c < 32; c++) o[c] = row[c];
    }
}

// ---------------------------------------------------------------------------
// Kernel 3: fused IPA attention (wave-specialized, pipelined).
// Block = (i, j-half).  Per tile (32 j):
//   [bar] W01: zB MFMA + 32-dot logits + exp -> p(t);  W23: O/O3 loops for t-1;
//         all: issue z loads for t+1
//   [bar] all: O_pair MFMA (tile t)
//   [bar] write staged z(t+1) to LDS
// Partial layout per block (stride 2560 f32):
//   [0:192) O | [192:480) O3 | [768:2304) Opair | [2304:2316) den
// ---------------------------------------------------------------------------
__global__ __launch_bounds__(256, 4) void ipa_main(
    const float* __restrict__ z,
    const float* __restrict__ Wb,
    const unsigned short* __restrict__ EQw, const unsigned short* __restrict__ EKw,
    const unsigned short* __restrict__ Vt, const unsigned short* __restrict__ V3t,
    float* __restrict__ part3)
{
    __shared__ __align__(16) unsigned short z_l[90 * 88];      // 15.8 KB
    __shared__ __align__(16) float          p_l[2][32 * 17];   // 4.3 KB
    __shared__ __align__(16) unsigned short pT_l[2][16 * 40];  // 2.5 KB
    __shared__ __align__(16) float          eq_l[12 * 33];     // 1.6 KB
    __shared__ __align__(16) unsigned short wbT_l[16 * 136];   // 4.3 KB

    const int i     = blockIdx.x >> 1;
    const int chunk = blockIdx.x & 1;
    const int t    = threadIdx.x;
    const int lane = t & 63;
    const int wv   = t >> 6;
    const int g    = lane >> 4;
    const int lm   = lane & 15;

    // ------- init -------
    for (int u = t; u < 384; u += 256) {
        int h = u >> 5, c = u & 31;
        eq_l[h*33 + c] = bf2f(EQw[((size_t)i*12 + h)*32 + c]);
    }
    for (int u = t; u < 1536; u += 256) {
        int h = u % 12, c = u / 12;
        wbT_l[h*136 + c] = f2bf(Wb[c*12 + h]);
    }
    for (int u = t; u < 512; u += 256)   // zero heads 12..15 (read by idle MFMA lanes)
        wbT_l[(12 + (u >> 7))*136 + (u & 127)] = 0;
    if (t < 160) { pT_l[0][480 + t] = 0; pT_l[1][480 + t] = 0; }

    // stage mapping (placed subtiles, stride 88 elems)
    const int jj  = t >> 3, c16 = t & 7;
    const float* zbase = z + ((size_t)i*768 + chunk*384 + jj)*128 + c16*16;
    const int chS  = (jj >> 2)*8 + c16;
    const int chP  = chS + HOFF(chS >> 4);
    const int sidx = chP*88 + (jj & 3)*16;

    // accumulators
    f32x4 opA = {0,0,0,0}, opB = {0,0,0,0};
    float oa = 0, ob = 0, oc2 = 0;
    float o3x = 0, o3y = 0, o3z = 0;
    float dn = 0;
    const int w = t - 128;   // W23 lane id 0..127 (valid when wv>=2)

    // ------- prologue: stage tile 0 -------
    {
        float4 f0 = *(const float4*)(zbase + 0);
        float4 f1 = *(const float4*)(zbase + 4);
        float4 f2 = *(const float4*)(zbase + 8);
        float4 f3 = *(const float4*)(zbase + 12);
        uint4* dst = (uint4*)&z_l[sidx];
        dst[0] = uint4{pk2(f0.x,f0.y), pk2(f0.z,f0.w), pk2(f1.x,f1.y), pk2(f1.z,f1.w)};
        dst[1] = uint4{pk2(f2.x,f2.y), pk2(f2.z,f2.w), pk2(f3.x,f3.y), pk2(f3.z,f3.w)};
    }
    __syncthreads();

    // V-accumulation work for tile tt (run by W23 during iter tt+1 / epilogue)
    auto vwork = [&](int tt) {
        const int j0v = chunk*384 + tt*32;
        const float* pp = p_l[tt & 1];
        if (w < 96) {
            // one O item (row w) + one O3 item (p3 = w)
            short8 va[4];
            #pragma unroll
            for (int q = 0; q < 4; q++)
                va[q] = *(const short8*)(Vt + (size_t)w*768 + j0v + q*8);
            short8 v3[3][4];
            #pragma unroll
            for (int d = 0; d < 3; d++)
                #pragma unroll
                for (int q = 0; q < 4; q++)
                    v3[d][q] = *(const short8*)(V3t + (size_t)(w*3 + d)*768 + j0v + q*8);
            const int ohp = w >> 4, o3hp = w >> 3;
            #pragma unroll
            for (int j2 = 0; j2 < 32; j2++) {
                float p1 = pp[j2*17 + ohp];
                oa += p1 * bf2f((unsigned short)va[j2>>3][j2&7]);
                float pv = pp[j2*17 + o3hp];
                o3x += pv * bf2f((unsigned short)v3[0][j2>>3][j2&7]);
                o3y += pv * bf2f((unsigned short)v3[1][j2>>3][j2&7]);
                o3z += pv * bf2f((unsigned short)v3[2][j2>>3][j2&7]);
            }
        } else {
            // three O items (rows w, w+32, w+64)
            short8 va[4], vb[4], vc[4];
            #pragma unroll
            for (int q = 0; q < 4; q++) {
                va[q] = *(const short8*)(Vt + (size_t)w*768      + j0v + q*8);
                vb[q] = *(const short8*)(Vt + (size_t)(w+32)*768 + j0v + q*8);
                vc[q] = *(const short8*)(Vt + (size_t)(w+64)*768 + j0v + q*8);
            }
            const int ha = w >> 4, hb = ha + 2, hc = ha + 4;
            #pragma unroll
            for (int j2 = 0; j2 < 32; j2++) {
                oa  += pp[j2*17 + ha] * bf2f((unsigned short)va[j2>>3][j2&7]);
                ob  += pp[j2*17 + hb] * bf2f((unsigned short)vb[j2>>3][j2&7]);
                oc2 += pp[j2*17 + hc] * bf2f((unsigned short)vc[j2>>3][j2&7]);
            }
        }
    };

    // ------- main loop -------
    for (int tile = 0; tile < 12; tile++) {
        const int j0  = chunk*384 + tile*32;
        const int cur = tile & 1, prv = cur ^ 1;
        const bool more = (tile < 11);

        // issue z loads for next tile early
        float4 zf0, zf1, zf2, zf3;
        if (more) {
            const float* zp = zbase + (size_t)(tile + 1) * 4096;
            zf0 = *(const float4*)(zp + 0);
            zf1 = *(const float4*)(zp + 4);
            zf2 = *(const float4*)(zp + 8);
            zf3 = *(const float4*)(zp + 12);
        }

        if (wv < 2) {
            // ---- B1: zB = z@Wb via MFMA (rows wv*16 + lm) ----
            f32x4 ab = {0,0,0,0};
            #pragma unroll
            for (int ks = 0; ks < 4; ks++) {
                short8 bf = *(const short8*)&wbT_l[lm*136 + ks*32 + g*8];
                int jr = wv*16 + lm;
                int ch = (jr >> 2)*8 + ks*2 + (g >> 1);
                int cp = ch + HOFF(ch >> 4);
                short8 a = *(const short8*)&z_l[cp*88 + (jr & 3)*16 + (g & 1)*8];
                ab = __builtin_amdgcn_mfma_f32_16x16x32_bf16(a, bf, ab, 0, 0, 0);
            }
            // ---- B2: finish logits for own rows (lane h = lm, rows 4g+r) ----
            if (lm < 12) {
                const float* eqh = eq_l + lm*33;
                #pragma unroll
                for (int r = 0; r < 4; r++) {
                    int jl = wv*16 + g*4 + r;
                    int j  = j0 + jl;
                    const unsigned short* ek = EKw + ((size_t)j*12 + lm)*32;
                    short8 e0 = *(const short8*)(ek);
                    short8 e1 = *(const short8*)(ek + 8);
                    short8 e2 = *(const short8*)(ek + 16);
                    short8 e3 = *(const short8*)(ek + 24);
                    float acc = ab[r] * NS_B;
                    #pragma unroll
                    for (int c = 0; c < 8; c++) acc += eqh[c]      * bf2f((unsigned short)e0[c]);
                    #pragma unroll
                    for (int c = 0; c < 8; c++) acc += eqh[8 + c]  * bf2f((unsigned short)e1[c]);
                    #pragma unroll
                    for (int c = 0; c < 8; c++) acc += eqh[16 + c] * bf2f((unsigned short)e2[c]);
                    #pragma unroll
                    for (int c = 0; c < 6; c++) acc += eqh[24 + c] * bf2f((unsigned short)e3[c]);
                    // mask columns as an ISOLATED pair: exact 0 when mi=mj=1,
                    // ~-1e9 when masked. Never route +-1e9 through acc serially.
                    float mterm = eqh[30] * bf2f((unsigned short)e3[6]);
                    mterm += eqh[31] * bf2f((unsigned short)e3[7]);
                    acc += mterm;
                    float p = __expf(acc);
                    p_l[cur][jl*17 + lm]  = p;
                    pT_l[cur][lm*40 + jl] = f2bf(p);
                }
            } else if (wv == 0 && lm < 15 && tile > 0) {
                // den for tile-1 (wave0 lanes lm 12..14)
                const int dh = g*3 + (lm - 12);
                const float* pp = p_l[prv];
                #pragma unroll
                for (int j2 = 0; j2 < 32; j2++) dn += pp[j2*17 + dh];
            }
        } else {
            if (tile > 0) vwork(tile - 1);
        }

        // pack staged z
        uint4 s0, s1;
        if (more) {
            s0 = uint4{pk2(zf0.x,zf0.y), pk2(zf0.z,zf0.w), pk2(zf1.x,zf1.y), pk2(zf1.z,zf1.w)};
            s1 = uint4{pk2(zf2.x,zf2.y), pk2(zf2.z,zf2.w), pk2(zf3.x,zf3.y), pk2(zf3.z,zf3.w)};
        }
        __syncthreads();   // p(t)/pT(t) ready; z_l still tile t

        // ---- O_pair MFMA (tile t, all waves) ----
        {
            const int nt0 = wv*2;
            short8 ap = *(const short8*)((const char*)pT_l[cur] + lm*80 + g*16);
            short8 b0, b1;
            #pragma unroll
            for (int e = 0; e < 8; e++) {
                int jje = g*8 + e;
                int su  = (jje >> 2)*8;
                int ro  = (jje & 3)*16;
                int cp0 = su + nt0 + HOFF(g);
                b0[e] = (short)z_l[cp0*88 + ro + lm];
                b1[e] = (short)z_l[(cp0 + 1)*88 + ro + lm];
            }
            opA = __builtin_amdgcn_mfma_f32_16x16x32_bf16(ap, b0, opA, 0, 0, 0);
            opB = __builtin_amdgcn_mfma_f32_16x16x32_bf16(ap, b1, opB, 0, 0, 0);
        }
        __syncthreads();   // z_l reads done

        if (more) {
            uint4* dst = (uint4*)&z_l[sidx];
            dst[0] = s0; dst[1] = s1;
        }
        __syncthreads();   // stage-write visible for next B1
    }

    // ------- epilogue: V-work and den for tile 11 -------
    if (wv >= 2) vwork(11);
    if (wv == 0 && lm >= 12 && lm < 15) {
        const int dh = g*3 + (lm - 12);
        const float* pp = p_l[1];   // 11 & 1
        #pragma unroll
        for (int j2 = 0; j2 < 32; j2++) dn += pp[j2*17 + dh];
    }

    // ------- write partials -------
    float* pb = part3 + (size_t)blockIdx.x * 2560;
    if (wv >= 2) {
        pb[w] = oa;
        if (w < 96) {
            pb[192 + w*3 + 0] = o3x;
            pb[192 + w*3 + 1] = o3y;
            pb[192 + w*3 + 2] = o3z;
        } else {
            pb[w + 32] = ob;
            pb[w + 64] = oc2;
        }
    }
    if (wv == 0 && lm >= 12 && lm < 15) pb[2304 + g*3 + (lm - 12)] = dn;
    {
        const int nt0 = wv*2;
        #pragma unroll
        for (int r = 0; r < 4; r++) {
            int h = g*4 + r;
            if (h < 12) {
                pb[768 + h*128 + nt0*16 + lm]       = opA[r];
                pb[768 + h*128 + (nt0 + 1)*16 + lm] = opB[r];
            }
        }
    }
}

// ---------------------------------------------------------------------------
// Kernel 3b: combine 2 j-chunks, divide by den, rotate O3, write OF row.
// ---------------------------------------------------------------------------
__global__ __launch_bounds__(256) void combine_kernel(
    const float* __restrict__ part3, const float* __restrict__ rots,
    const float* __restrict__ trans, unsigned short* __restrict__ OF)
{
    const int i = blockIdx.x;
    const int t = threadIdx.x;
    const float* pa = part3 + (size_t)i*2*2560;
    const float* pb = pa + 2560;
    __shared__ float den_s[12];
    if (t < 12) den_s[t] = pa[2304 + t] + pb[2304 + t];
    __syncthreads();

    const size_t ofb = (size_t)i * 2112;
    if (t < 192) OF[ofb + t] = f2bf((pa[t] + pb[t]) / den_s[t >> 4]);
    if (t < 96) {
        int h = t >> 3, v = t & 7;
        float den = den_s[h];
        int base = 192 + t*3;
        float m0 = (pa[base+0] + pb[base+0]) / den - trans[i*3+0];
        float m1 = (pa[base+1] + pb[base+1]) / den - trans[i*3+1];
        float m2 = (pa[base+2] + pb[base+2]) / den - trans[i*3+2];
        const float* R = rots + (size_t)i*9;
        float r0v = R[0]*m0 + R[3]*m1 + R[6]*m2;
        float r1v = R[1]*m0 + R[4]*m1 + R[7]*m2;
        float r2v = R[2]*m0 + R[5]*m1 + R[8]*m2;
        float nrm = sqrtf(r0v*r0v + r1v*r1v + r2v*r2v + 1e-20f);
        int hv = h*8 + v;
        OF[ofb + 192 + hv] = f2bf(r0v);
        OF[ofb + 288 + hv] = f2bf(r1v);
        OF[ofb + 384 + hv] = f2bf(r2v);
        OF[ofb + 480 + hv] = f2bf(nrm);
    }
    for (int u = t; u < 1536; u += 256) {
        OF[ofb + 576 + u] = f2bf((pa[768 + u] + pb[768 + u]) / den_s[u >> 7]);
    }
}

// ---------------------------------------------------------------------------
// Kernel 4: out = OF(bf16) @ Wo (f32), K-split partials (deterministic).
// ---------------------------------------------------------------------------
__global__ __launch_bounds__(256) void out_gemm(
    const unsigned short* __restrict__ OF, const float* __restrict__ Wo,
    float* __restrict__ part)
{
    __shared__ __align__(16) float aT[32 * 132];
    __shared__ __align__(16) float bt[32 * 68];
    const int t  = threadIdx.x;
    const int i0 = blockIdx.x * 128;
    const int c0 = blockIdx.y * 64;
    const int k0 = blockIdx.z * 352;
    const int r0 = (t & 15) * 8;
    const int c4 = (t >> 4) * 4;

    float acc[8][4] = {};

    for (int kt = 0; kt < 11; kt++) {
        const int kk0 = k0 + kt*32;
        __syncthreads();
        {
            int r = t >> 1, kh = (t & 1) * 16;
            const unsigned short* apg = OF + (size_t)(i0 + r)*2112 + kk0 + kh;
            short8 v0 = *(const short8*)apg;
            short8 v1 = *(const short8*)(apg + 8);
            #pragma unroll
            for (int e = 0; e < 8; e++) aT[(kh + e)*132 + r]     = bf2f((unsigned short)v0[e]);
            #pragma unroll
            for (int e = 0; e < 8; e++) aT[(kh + 8 + e)*132 + r] = bf2f((unsigned short)v1[e]);
        }
        {
            int k = t >> 3, c8 = (t & 7) * 8;
            const float* wpg = Wo + (size_t)(kk0 + k)*384 + c0 + c8;
            *(float4*)&bt[k*68 + c8]     = *(const float4*)wpg;
            *(float4*)&bt[k*68 + c8 + 4] = *(const float4*)(wpg + 4);
        }
        __syncthreads();
        #pragma unroll 4
        for (int kk = 0; kk < 32; kk++) {
            float4 a0 = *(float4*)&aT[kk*132 + r0];
            float4 a1 = *(float4*)&aT[kk*132 + r0 + 4];
            float4 bv = *(float4*)&bt[kk*68 + c4];
            #pragma unroll
            for (int ci = 0; ci < 4; ci++) {
                float b = ((const float*)&bv)[ci];
                acc[0][ci] += ((const float*)&a0)[0] * b;
                acc[1][ci] += ((const float*)&a0)[1] * b;
                acc[2][ci] += ((const float*)&a0)[2] * b;
                acc[3][ci] += ((const float*)&a0)[3] * b;
                acc[4][ci] += ((const float*)&a1)[0] * b;
                acc[5][ci] += ((const float*)&a1)[1] * b;
                acc[6][ci] += ((const float*)&a1)[2] * b;
                acc[7][ci] += ((const float*)&a1)[3] * b;
            }
        }
    }

    float* pbv = part + (size_t)blockIdx.z * 294912;
    #pragma unroll
    for (int ri = 0; ri < 8; ri++) {
        float4 o = {acc[ri][0], acc[ri][1], acc[ri][2], acc[ri][3]};
        *(float4*)&pbv[(size_t)(i0 + r0 + ri)*384 + c0 + c4] = o;
    }
}

// ---------------------------------------------------------------------------
// Kernel 5: reduce 6 K-split partials + bias -> out (f32)
// ---------------------------------------------------------------------------
__global__ __launch_bounds__(256) void reduce_out(
    const float* __restrict__ part, const float* __restrict__ bo,
    float* __restrict__ out)
{
    int idx = blockIdx.x * 256 + threadIdx.x;
    float v = bo[idx % 384];
    #pragma unroll
    for (int s = 0; s < 6; s++) v += part[(size_t)s * 294912 + idx];
    out[idx] = v;
}

// ---------------------------------------------------------------------------
extern "C" void kernel_launch(void* const* d_in, const int* in_sizes, int n_in,
                              void* d_out, int out_size, void* d_ws, size_t ws_size,
                              hipStream_t stream) {
    const float* s     = (const float*)d_in[0];
    const float* z     = (const float*)d_in[1];
    const float* rots  = (const float*)d_in[2];
    const float* trans = (const float*)d_in[3];
    const float* mask  = (const float*)d_in[4];
    const float* Wq    = (const float*)d_in[5];
    const float* bq    = (const float*)d_in[6];
    const float* Wkv   = (const float*)d_in[7];
    const float* bkv   = (const float*)d_in[8];
    const float* Wq3   = (const float*)d_in[9];
    const float* bq3   = (const float*)d_in[10];
    const float* Wkv3  = (const float*)d_in[11];
    const float* bkv3  = (const float*)d_in[12];
    const float* Wb    = (const float*)d_in[13];
    const float* bb    = (const float*)d_in[14];
    const float* hw    = (const float*)d_in[15];
    const float* Wo    = (const float*)d_in[16];
    const float* bo    = (const float*)d_in[17];
    float* out = (float*)d_out;

    char* ws = (char*)d_ws;
    float*          Qw   = (float*)(ws + 0);              // 589824 B
    float*          Q3w  = (float*)(ws + 589824);         // 442368 B
    unsigned short* Kw   = (unsigned short*)(ws + 1032192);  // 294912 B
    unsigned short* Vt   = (unsigned short*)(ws + 1327104);  // 294912 B
    float*          K3w  = (float*)(ws + 1622016);        // 442368 B
    unsigned short* V3t  = (unsigned short*)(ws + 2064384);  // 442368 B
    float*          P3q  = (float*)(ws + 2506752);        // 442368 B
    float*          P3kv = (float*)(ws + 2949120);        // 1327104 B
    unsigned short* EQw  = (unsigned short*)(ws + 4276224);  // 589824 B
    unsigned short* EKw  = (unsigned short*)(ws + 4866048);  // 589824 B
    unsigned short* OF   = (unsigned short*)(ws + 5455872);  // 3244032 B
    float*          part3 = (float*)(ws + 8699904);       // 15728640 B
    float*          part  = (float*)(ws + 8699904);       // shared (disjoint lifetime)

    proj_kernel<<<dim3(24, 9), 256, 0, stream>>>(
        s, Wq, bq, Wkv, bkv, Wq3, bq3, Wkv3, bkv3, Qw, Kw, Vt, P3q, P3kv);
    rot3_kernel<<<768, 192, 0, stream>>>(P3q, P3kv, rots, trans, Q3w, K3w, V3t);
    ek_kernel<<<192, 256, 0, stream>>>(Qw, Kw, Q3w, K3w, mask, hw, bb, EQw, EKw);
    ipa_main<<<1536, 256, 0, stream>>>(z, Wb, EQw, EKw, Vt, V3t, part3);
    combine_kernel<<<768, 256, 0, stream>>>(part3, rots, trans, OF);
    out_gemm<<<dim3(6, 6, 6), 256, 0, stream>>>(OF, Wo, part);
    reduce_out<<<1152, 256, 0, stream>>>(part, bo, out);
}

// Round 7
// 307.887 us; speedup vs baseline: 1.5362x; 1.5362x over previous
//
#include <hip/hip_runtime.h>
#include <cstdint>

// ---------------------------------------------------------------------------
// InvariantPointAttention fused kernel set for MI355X (gfx950)
// N=768, C_S=384, C_Z=128, C_IPA=16, H=12, NQ=4, NV=8
// ---------------------------------------------------------------------------

typedef __attribute__((ext_vector_type(8))) short short8;
typedef __attribute__((ext_vector_type(4))) short short4_t;
typedef __attribute__((ext_vector_type(4))) float f32x4;

__device__ __forceinline__ unsigned short f2bf(float f) {
    unsigned u = __float_as_uint(f);
    u = (u + 0x7FFFu + ((u >> 16) & 1u)) >> 16;   // RNE
    return (unsigned short)u;
}
__device__ __forceinline__ float bf2f(unsigned short s) {
    return __uint_as_float(((unsigned)s) << 16);
}
__device__ __forceinline__ unsigned pk2(float lo, float hi) {
    return (unsigned)f2bf(lo) | ((unsigned)f2bf(hi) << 16);
}
// subtile placement offset: H[g] = {0,6,20,26}; 44*H[g] mod 32 = {0,8,16,24}
__device__ __forceinline__ int HOFF(int gg) {
    return gg * 6 + ((gg & 2) << 2);
}

#define NS_QK  0.14433756729740643f   // sqrt(1/48)
#define NS_B   0.5773502691896258f    // sqrt(1/3)
#define NS_HW  0.13608276348795434f   // sqrt(1/54)

// ---------------------------------------------------------------------------
// Kernel 1: fused projection GEMM.  s (768x384) @ [Wq|Wkv|Wq3|Wkv3] (384x1152)
// ---------------------------------------------------------------------------
__global__ __launch_bounds__(256) void proj_kernel(
    const float* __restrict__ s,
    const float* __restrict__ Wq,   const float* __restrict__ bq,
    const float* __restrict__ Wkv,  const float* __restrict__ bkv,
    const float* __restrict__ Wq3,  const float* __restrict__ bq3,
    const float* __restrict__ Wkv3, const float* __restrict__ bkv3,
    float* __restrict__ Qw, unsigned short* __restrict__ Kw,
    unsigned short* __restrict__ Vt,
    float* __restrict__ P3q, float* __restrict__ P3kv)
{
    __shared__ __align__(16) float s_lds[32 * 384];
    const int t  = threadIdx.x;
    const int r0 = blockIdx.x * 32;
    const int c0 = blockIdx.y * 128;

    for (int u = t; u < 3072; u += 256) {
        int r = u / 96, c4 = u - r * 96;
        *(float4*)&s_lds[r * 384 + c4 * 4] =
            *(const float4*)&s[(size_t)(r0 + r) * 384 + c4 * 4];
    }
    __syncthreads();

    const int rg = t >> 6;
    const int lc = t & 63;
    const int colA = c0 + lc;
    const int colB = c0 + lc + 64;

    const float *wpA, *wpB; int ldA, ldB; float biasA, biasB;
    {
        int col = colA;
        if (col < 192)      { wpA = Wq   + col;       ldA = 192; biasA = bq[col]; }
        else if (col < 576) { wpA = Wkv  + (col-192); ldA = 384; biasA = bkv[col-192]; }
        else if (col < 720) { wpA = Wq3  + (col-576); ldA = 144; biasA = bq3[col-576]; }
        else                { wpA = Wkv3 + (col-720); ldA = 432; biasA = bkv3[col-720]; }
        col = colB;
        if (col < 192)      { wpB = Wq   + col;       ldB = 192; biasB = bq[col]; }
        else if (col < 576) { wpB = Wkv  + (col-192); ldB = 384; biasB = bkv[col-192]; }
        else if (col < 720) { wpB = Wq3  + (col-576); ldB = 144; biasB = bq3[col-576]; }
        else                { wpB = Wkv3 + (col-720); ldB = 432; biasB = bkv3[col-720]; }
    }

    float acc0[8] = {}, acc1[8] = {};
    for (int k = 0; k < 384; k += 4) {
        float4 sv[8];
        #pragma unroll
        for (int r = 0; r < 8; r++)
            sv[r] = *(const float4*)&s_lds[(rg*8 + r) * 384 + k];
        #pragma unroll
        for (int kk = 0; kk < 4; kk++) {
            float w0 = wpA[(k + kk) * ldA];
            float w1 = wpB[(k + kk) * ldB];
            #pragma unroll
            for (int r = 0; r < 8; r++) {
                float sval = ((const float*)&sv[r])[kk];
                acc0[r] += sval * w0;
                acc1[r] += sval * w1;
            }
        }
    }

    #pragma unroll
    for (int q = 0; q < 2; q++) {
        int col   = q ? colB : colA;
        float bia = q ? biasB : biasA;
        #pragma unroll
        for (int r = 0; r < 8; r++) {
            int row = r0 + rg*8 + r;
            float v = (q ? acc1[r] : acc0[r]) + bia;
            if (col < 192) {
                Qw[(size_t)row*192 + col] = v;
            } else if (col < 576) {
                int c = col - 192, h = c >> 5, sub = c & 31;
                if (sub < 16) Kw[(size_t)row*192 + h*16 + sub] = f2bf(v);
                else          Vt[(size_t)(h*16 + (sub-16))*768 + row] = f2bf(v);
            } else if (col < 720) {
                P3q[(size_t)row*144 + (col-576)] = v;
            } else {
                P3kv[(size_t)row*432 + (col-720)] = v;
            }
        }
    }
}

// ---------------------------------------------------------------------------
// Kernel 2: rotate/translate projected points.
// ---------------------------------------------------------------------------
__global__ __launch_bounds__(192) void rot3_kernel(
    const float* __restrict__ P3q, const float* __restrict__ P3kv,
    const float* __restrict__ rots, const float* __restrict__ trans,
    float* __restrict__ Q3w, float* __restrict__ K3w,
    unsigned short* __restrict__ V3t)
{
    const int n = blockIdx.x;
    const int t = threadIdx.x;
    float R[9];
    #pragma unroll
    for (int u = 0; u < 9; u++) R[u] = rots[n*9 + u];
    float T0 = trans[n*3+0], T1 = trans[n*3+1], T2 = trans[n*3+2];

    float p0, p1, p2;
    if (t < 48) {
        p0 = P3q[(size_t)n*144 + t];
        p1 = P3q[(size_t)n*144 + 48 + t];
        p2 = P3q[(size_t)n*144 + 96 + t];
    } else {
        int k = t - 48;
        p0 = P3kv[(size_t)n*432 + k];
        p1 = P3kv[(size_t)n*432 + 144 + k];
        p2 = P3kv[(size_t)n*432 + 288 + k];
    }
    float o0 = R[0]*p0 + R[1]*p1 + R[2]*p2 + T0;
    float o1 = R[3]*p0 + R[4]*p1 + R[5]*p2 + T1;
    float o2 = R[6]*p0 + R[7]*p1 + R[8]*p2 + T2;

    if (t < 48) {
        Q3w[(size_t)n*144 + t*3 + 0] = o0;
        Q3w[(size_t)n*144 + t*3 + 1] = o1;
        Q3w[(size_t)n*144 + t*3 + 2] = o2;
    } else {
        int k = t - 48, h = k / 12, m = k % 12;
        if (m < 4) {
            size_t base = (size_t)n*144 + (h*4 + m)*3;
            K3w[base+0] = o0; K3w[base+1] = o1; K3w[base+2] = o2;
        } else {
            int rv = (h*8 + (m-4))*3;
            V3t[(size_t)(rv+0)*768 + n] = f2bf(o0);
            V3t[(size_t)(rv+1)*768 + n] = f2bf(o1);
            V3t[(size_t)(rv+2)*768 + n] = f2bf(o2);
        }
    }
}

// ---------------------------------------------------------------------------
// Kernel 2b: build extended logit vectors (see R5/R6 notes).
// cols 30/31 accumulate as ISOLATED pair (exact cancel at S=31616).
// ---------------------------------------------------------------------------
__global__ __launch_bounds__(256) void ek_kernel(
    const float* __restrict__ Qw, const unsigned short* __restrict__ Kw,
    const float* __restrict__ Q3w, const float* __restrict__ K3w,
    const float* __restrict__ mask, const float* __restrict__ hw,
    const float* __restrict__ bb,
    unsigned short* __restrict__ EQw, unsigned short* __restrict__ EKw)
{
    const int idx = blockIdx.x * 4 + (threadIdx.x >> 6);
    const int h   = threadIdx.x & 63;
    if (h >= 12) return;
    const float hws = log1pf(__expf(hw[h])) * NS_HW;
    const float mi  = mask[idx];
    const float S   = 31616.0f;   // bf16-exact; S^2 exact in f32

    unsigned short row[32];
    // EK
    {
        const unsigned short* kp = Kw + (size_t)idx*192 + h*16;
        #pragma unroll
        for (int c = 0; c < 16; c++) row[c] = kp[c];
        const float* k3 = K3w + (size_t)idx*144 + h*12;
        float kn = 0.0f;
        #pragma unroll
        for (int e = 0; e < 12; e++) {
            unsigned short b = f2bf(k3[e]);
            row[16+e] = b;
            float f = bf2f(b); kn += f*f;
        }
        row[28] = f2bf(bb[h]*NS_B - 0.5f*hws*kn);
        row[29] = f2bf(1.0f);
        row[30] = f2bf(mi * S);
        row[31] = f2bf(-S);
        unsigned short* o = EKw + ((size_t)idx*12 + h)*32;
        #pragma unroll
        for (int c = 0; c < 32; c++) o[c] = row[c];
    }
    // EQ
    {
        const float* qp = Qw + (size_t)idx*192 + h*16;
        #pragma unroll
        for (int c = 0; c < 16; c++) row[c] = f2bf(qp[c] * NS_QK);
        const float* q3 = Q3w + (size_t)idx*144 + h*12;
        float qn = 0.0f;
        #pragma unroll
        for (int e = 0; e < 12; e++) {
            float f = q3[e];
            row[16+e] = f2bf(f * hws);
            qn += f*f;
        }
        row[28] = f2bf(1.0f);
        row[29] = f2bf(-0.5f*hws*qn);
        row[30] = f2bf(mi * S);
        row[31] = f2bf(S);
        unsigned short* o = EQw + ((size_t)idx*12 + h)*32;
        #pragma unroll
        for (int c = 0; c < 32; c++) o[c] = row[c];
    }
}

// ---------------------------------------------------------------------------
// Kernel 3: fused IPA attention (wave-specialized, pipelined, SLIM registers).
// Block = (i, j-half).  Per tile: W01 logits(t) | W23 V-work(t-1)+den, then
// all waves O_pair MFMA(t), then stage z(t+1).
// Partial layout per block (stride 2560 f32):
//   [0:192) O | [192:480) O3 | [768:2304) Opair | [2304:2316) den
// ---------------------------------------------------------------------------
__global__ __launch_bounds__(256, 2) void ipa_main(
    const float* __restrict__ z,
    const float* __restrict__ Wb,
    const unsigned short* __restrict__ EQw, const unsigned short* __restrict__ EKw,
    const unsigned short* __restrict__ Vt, const unsigned short* __restrict__ V3t,
    float* __restrict__ part3)
{
    __shared__ __align__(16) unsigned short z_l[90 * 88];      // 15.8 KB
    __shared__ __align__(16) float          p_l[2][32 * 17];   // 4.3 KB
    __shared__ __align__(16) unsigned short pT_l[2][16 * 40];  // 2.5 KB
    __shared__ __align__(16) float          eq_l[12 * 33];     // 1.6 KB
    __shared__ __align__(16) unsigned short wbT_l[16 * 136];   // 4.3 KB

    const int i     = blockIdx.x >> 1;
    const int chunk = blockIdx.x & 1;
    const int t    = threadIdx.x;
    const int lane = t & 63;
    const int wv   = t >> 6;
    const int g    = lane >> 4;
    const int lm   = lane & 15;

    // ------- init -------
    for (int u = t; u < 384; u += 256) {
        int h = u >> 5, c = u & 31;
        eq_l[h*33 + c] = bf2f(EQw[((size_t)i*12 + h)*32 + c]);
    }
    for (int u = t; u < 1536; u += 256) {
        int h = u % 12, c = u / 12;
        wbT_l[h*136 + c] = f2bf(Wb[c*12 + h]);
    }
    for (int u = t; u < 512; u += 256)   // zero heads 12..15
        wbT_l[(12 + (u >> 7))*136 + (u & 127)] = 0;
    if (t < 160) { pT_l[0][480 + t] = 0; pT_l[1][480 + t] = 0; }

    // stage mapping (placed subtiles, stride 88 elems)
    const int jj  = t >> 3, c16 = t & 7;
    const float* zbase = z + ((size_t)i*768 + chunk*384 + jj)*128 + c16*16;
    const int chS  = (jj >> 2)*8 + c16;
    const int chP  = chS + HOFF(chS >> 4);
    const int sidx = chP*88 + (jj & 3)*16;

    // accumulators
    f32x4 opA = {0,0,0,0}, opB = {0,0,0,0};
    float oa = 0, ob = 0, oc2 = 0;
    float o3x = 0, o3y = 0, o3z = 0;
    float dn = 0;
    const int w = t - 128;   // W23 lane id 0..127 (valid when wv>=2)

    // ------- prologue: stage tile 0 -------
    {
        float4 f0 = *(const float4*)(zbase + 0);
        float4 f1 = *(const float4*)(zbase + 4);
        float4 f2 = *(const float4*)(zbase + 8);
        float4 f3 = *(const float4*)(zbase + 12);
        uint4* dst = (uint4*)&z_l[sidx];
        dst[0] = uint4{pk2(f0.x,f0.y), pk2(f0.z,f0.w), pk2(f1.x,f1.y), pk2(f1.z,f1.w)};
        dst[1] = uint4{pk2(f2.x,f2.y), pk2(f2.z,f2.w), pk2(f3.x,f3.y), pk2(f3.z,f3.w)};
    }
    __syncthreads();

    // V-accumulation work for tile tt (run by W23), STREAMED in q-chunks to
    // keep <=4 short8 live (R6 held 16 -> spilled).
    auto vwork = [&](int tt) {
        const int j0v = chunk*384 + tt*32;
        const float* pp = p_l[tt & 1];
        if (w < 96) {
            const int ohp = w >> 4, o3hp = w >> 3;
            const unsigned short* vp  = Vt  + (size_t)w*768 + j0v;
            const unsigned short* v3p = V3t + (size_t)(w*3)*768 + j0v;
            #pragma unroll
            for (int q = 0; q < 4; q++) {
                short8 va = *(const short8*)(vp + q*8);
                short8 v0 = *(const short8*)(v3p + q*8);
                short8 v1 = *(const short8*)(v3p + 768 + q*8);
                short8 v2 = *(const short8*)(v3p + 1536 + q*8);
                #pragma unroll
                for (int e = 0; e < 8; e++) {
                    int j2 = q*8 + e;
                    float p1 = pp[j2*17 + ohp];
                    oa += p1 * bf2f((unsigned short)va[e]);
                    float pv = pp[j2*17 + o3hp];
                    o3x += pv * bf2f((unsigned short)v0[e]);
                    o3y += pv * bf2f((unsigned short)v1[e]);
                    o3z += pv * bf2f((unsigned short)v2[e]);
                }
            }
        } else {
            const int ha = w >> 4, hb = ha + 2, hc = ha + 4;
            const int dh = w - 96;   // den head for first 12 threads
            const unsigned short* vp = Vt + (size_t)w*768 + j0v;
            #pragma unroll
            for (int q = 0; q < 4; q++) {
                short8 va = *(const short8*)(vp + q*8);
                short8 vb = *(const short8*)(vp + 768*32 + q*8);
                short8 vc = *(const short8*)(vp + 768*64 + q*8);
                #pragma unroll
                for (int e = 0; e < 8; e++) {
                    int j2 = q*8 + e;
                    oa  += pp[j2*17 + ha] * bf2f((unsigned short)va[e]);
                    ob  += pp[j2*17 + hb] * bf2f((unsigned short)vb[e]);
                    oc2 += pp[j2*17 + hc] * bf2f((unsigned short)vc[e]);
                }
            }
            if (dh < 12) {
                #pragma unroll
                for (int j2 = 0; j2 < 32; j2++) dn += pp[j2*17 + dh];
            }
        }
    };

    // ------- main loop -------
    for (int tile = 0; tile < 12; tile++) {
        const int j0  = chunk*384 + tile*32;
        const int cur = tile & 1;
        const bool more = (tile < 11);

        // issue z loads for next tile early (held live across branch work)
        float4 zf0, zf1, zf2, zf3;
        if (more) {
            const float* zp = zbase + (size_t)(tile + 1) * 4096;
            zf0 = *(const float4*)(zp + 0);
            zf1 = *(const float4*)(zp + 4);
            zf2 = *(const float4*)(zp + 8);
            zf3 = *(const float4*)(zp + 12);
        }

        if (wv < 2) {
            // ---- B1: zB = z@Wb via MFMA (rows wv*16 + lm) ----
            f32x4 ab = {0,0,0,0};
            #pragma unroll
            for (int ks = 0; ks < 4; ks++) {
                short8 bf = *(const short8*)&wbT_l[lm*136 + ks*32 + g*8];
                int jr = wv*16 + lm;
                int ch = (jr >> 2)*8 + ks*2 + (g >> 1);
                int cp = ch + HOFF(ch >> 4);
                short8 a = *(const short8*)&z_l[cp*88 + (jr & 3)*16 + (g & 1)*8];
                ab = __builtin_amdgcn_mfma_f32_16x16x32_bf16(a, bf, ab, 0, 0, 0);
            }
            // ---- B2: finish logits for own rows (lane h = lm, rows 4g+r) ----
            if (lm < 12) {
                const float* eqh = eq_l + lm*33;
                #pragma unroll
                for (int r = 0; r < 4; r++) {
                    int jl = wv*16 + g*4 + r;
                    int j  = j0 + jl;
                    const unsigned short* ek = EKw + ((size_t)j*12 + lm)*32;
                    short8 e0 = *(const short8*)(ek);
                    short8 e1 = *(const short8*)(ek + 8);
                    short8 e2 = *(const short8*)(ek + 16);
                    short8 e3 = *(const short8*)(ek + 24);
                    float acc = ab[r] * NS_B;
                    #pragma unroll
                    for (int c = 0; c < 8; c++) acc += eqh[c]      * bf2f((unsigned short)e0[c]);
                    #pragma unroll
                    for (int c = 0; c < 8; c++) acc += eqh[8 + c]  * bf2f((unsigned short)e1[c]);
                    #pragma unroll
                    for (int c = 0; c < 8; c++) acc += eqh[16 + c] * bf2f((unsigned short)e2[c]);
                    #pragma unroll
                    for (int c = 0; c < 6; c++) acc += eqh[24 + c] * bf2f((unsigned short)e3[c]);
                    // mask columns as an ISOLATED pair (exact cancel)
                    float mterm = eqh[30] * bf2f((unsigned short)e3[6]);
                    mterm += eqh[31] * bf2f((unsigned short)e3[7]);
                    acc += mterm;
                    float p = __expf(acc);
                    p_l[cur][jl*17 + lm]  = p;
                    pT_l[cur][lm*40 + jl] = f2bf(p);
                }
            }
        } else {
            if (tile > 0) vwork(tile - 1);
        }

        // pack staged z
        uint4 s0, s1;
        if (more) {
            s0 = uint4{pk2(zf0.x,zf0.y), pk2(zf0.z,zf0.w), pk2(zf1.x,zf1.y), pk2(zf1.z,zf1.w)};
            s1 = uint4{pk2(zf2.x,zf2.y), pk2(zf2.z,zf2.w), pk2(zf3.x,zf3.y), pk2(zf3.z,zf3.w)};
        }
        __syncthreads();   // p(t)/pT(t) ready; z_l still tile t

        // ---- O_pair MFMA (tile t, all waves) ----
        {
            const int nt0 = wv*2;
            short8 ap = *(const short8*)((const char*)pT_l[cur] + lm*80 + g*16);
            short8 b0, b1;
            #pragma unroll
            for (int e = 0; e < 8; e++) {
                int jje = g*8 + e;
                int su  = (jje >> 2)*8;
                int ro  = (jje & 3)*16;
                int cp0 = su + nt0 + HOFF(g);
                b0[e] = (short)z_l[cp0*88 + ro + lm];
                b1[e] = (short)z_l[(cp0 + 1)*88 + ro + lm];
            }
            opA = __builtin_amdgcn_mfma_f32_16x16x32_bf16(ap, b0, opA, 0, 0, 0);
            opB = __builtin_amdgcn_mfma_f32_16x16x32_bf16(ap, b1, opB, 0, 0, 0);
        }
        __syncthreads();   // z_l reads done

        if (more) {
            uint4* dst = (uint4*)&z_l[sidx];
            dst[0] = s0; dst[1] = s1;
        }
        __syncthreads();   // stage-write visible for next B1
    }

    // ------- epilogue: V-work and den for tile 11 -------
    if (wv >= 2) vwork(11);

    // ------- write partials -------
    float* pb = part3 + (size_t)blockIdx.x * 2560;
    if (wv >= 2) {
        pb[w] = oa;
        if (w < 96) {
            pb[192 + w*3 + 0] = o3x;
            pb[192 + w*3 + 1] = o3y;
            pb[192 + w*3 + 2] = o3z;
        } else {
            pb[w + 32] = ob;
            pb[w + 64] = oc2;
            if (w - 96 < 12) pb[2304 + (w - 96)] = dn;
        }
    }
    {
        const int nt0 = wv*2;
        #pragma unroll
        for (int r = 0; r < 4; r++) {
            int h = g*4 + r;
            if (h < 12) {
                pb[768 + h*128 + nt0*16 + lm]       = opA[r];
                pb[768 + h*128 + (nt0 + 1)*16 + lm] = opB[r];
            }
        }
    }
}

// ---------------------------------------------------------------------------
// Kernel 3b: combine 2 j-chunks, divide by den, rotate O3, write OF row.
// ---------------------------------------------------------------------------
__global__ __launch_bounds__(256) void combine_kernel(
    const float* __restrict__ part3, const float* __restrict__ rots,
    const float* __restrict__ trans, unsigned short* __restrict__ OF)
{
    const int i = blockIdx.x;
    const int t = threadIdx.x;
    const float* pa = part3 + (size_t)i*2*2560;
    const float* pb = pa + 2560;
    __shared__ float den_s[12];
    if (t < 12) den_s[t] = pa[2304 + t] + pb[2304 + t];
    __syncthreads();

    const size_t ofb = (size_t)i * 2112;
    if (t < 192) OF[ofb + t] = f2bf((pa[t] + pb[t]) / den_s[t >> 4]);
    if (t < 96) {
        int h = t >> 3, v = t & 7;
        float den = den_s[h];
        int base = 192 + t*3;
        float m0 = (pa[base+0] + pb[base+0]) / den - trans[i*3+0];
        float m1 = (pa[base+1] + pb[base+1]) / den - trans[i*3+1];
        float m2 = (pa[base+2] + pb[base+2]) / den - trans[i*3+2];
        const float* R = rots + (size_t)i*9;
        float r0v = R[0]*m0 + R[3]*m1 + R[6]*m2;
        float r1v = R[1]*m0 + R[4]*m1 + R[7]*m2;
        float r2v = R[2]*m0 + R[5]*m1 + R[8]*m2;
        float nrm = sqrtf(r0v*r0v + r1v*r1v + r2v*r2v + 1e-20f);
        int hv = h*8 + v;
        OF[ofb + 192 + hv] = f2bf(r0v);
        OF[ofb + 288 + hv] = f2bf(r1v);
        OF[ofb + 384 + hv] = f2bf(r2v);
        OF[ofb + 480 + hv] = f2bf(nrm);
    }
    for (int u = t; u < 1536; u += 256) {
        OF[ofb + 576 + u] = f2bf((pa[768 + u] + pb[768 + u]) / den_s[u >> 7]);
    }
}

// ---------------------------------------------------------------------------
// Kernel 4: out = OF(bf16) @ Wo (f32), K-split partials (deterministic).
// ---------------------------------------------------------------------------
__global__ __launch_bounds__(256) void out_gemm(
    const unsigned short* __restrict__ OF, const float* __restrict__ Wo,
    float* __restrict__ part)
{
    __shared__ __align__(16) float aT[32 * 132];
    __shared__ __align__(16) float bt[32 * 68];
    const int t  = threadIdx.x;
    const int i0 = blockIdx.x * 128;
    const int c0 = blockIdx.y * 64;
    const int k0 = blockIdx.z * 352;
    const int r0 = (t & 15) * 8;
    const int c4 = (t >> 4) * 4;

    float acc[8][4] = {};

    for (int kt = 0; kt < 11; kt++) {
        const int kk0 = k0 + kt*32;
        __syncthreads();
        {
            int r = t >> 1, kh = (t & 1) * 16;
            const unsigned short* apg = OF + (size_t)(i0 + r)*2112 + kk0 + kh;
            short8 v0 = *(const short8*)apg;
            short8 v1 = *(const short8*)(apg + 8);
            #pragma unroll
            for (int e = 0; e < 8; e++) aT[(kh + e)*132 + r]     = bf2f((unsigned short)v0[e]);
            #pragma unroll
            for (int e = 0; e < 8; e++) aT[(kh + 8 + e)*132 + r] = bf2f((unsigned short)v1[e]);
        }
        {
            int k = t >> 3, c8 = (t & 7) * 8;
            const float* wpg = Wo + (size_t)(kk0 + k)*384 + c0 + c8;
            *(float4*)&bt[k*68 + c8]     = *(const float4*)wpg;
            *(float4*)&bt[k*68 + c8 + 4] = *(const float4*)(wpg + 4);
        }
        __syncthreads();
        #pragma unroll 4
        for (int kk = 0; kk < 32; kk++) {
            float4 a0 = *(float4*)&aT[kk*132 + r0];
            float4 a1 = *(float4*)&aT[kk*132 + r0 + 4];
            float4 bv = *(float4*)&bt[kk*68 + c4];
            #pragma unroll
            for (int ci = 0; ci < 4; ci++) {
                float b = ((const float*)&bv)[ci];
                acc[0][ci] += ((const float*)&a0)[0] * b;
                acc[1][ci] += ((const float*)&a0)[1] * b;
                acc[2][ci] += ((const float*)&a0)[2] * b;
                acc[3][ci] += ((const float*)&a0)[3] * b;
                acc[4][ci] += ((const float*)&a1)[0] * b;
                acc[5][ci] += ((const float*)&a1)[1] * b;
                acc[6][ci] += ((const float*)&a1)[2] * b;
                acc[7][ci] += ((const float*)&a1)[3] * b;
            }
        }
    }

    float* pbv = part + (size_t)blockIdx.z * 294912;
    #pragma unroll
    for (int ri = 0; ri < 8; ri++) {
        float4 o = {acc[ri][0], acc[ri][1], acc[ri][2], acc[ri][3]};
        *(float4*)&pbv[(size_t)(i0 + r0 + ri)*384 + c0 + c4] = o;
    }
}

// ---------------------------------------------------------------------------
// Kernel 5: reduce 6 K-split partials + bias -> out (f32)
// ---------------------------------------------------------------------------
__global__ __launch_bounds__(256) void reduce_out(
    const float* __restrict__ part, const float* __restrict__ bo,
    float* __restrict__ out)
{
    int idx = blockIdx.x * 256 + threadIdx.x;
    float v = bo[idx % 384];
    #pragma unroll
    for (int s = 0; s < 6; s++) v += part[(size_t)s * 294912 + idx];
    out[idx] = v;
}

// ---------------------------------------------------------------------------
extern "C" void kernel_launch(void* const* d_in, const int* in_sizes, int n_in,
                              void* d_out, int out_size, void* d_ws, size_t ws_size,
                              hipStream_t stream) {
    const float* s     = (const float*)d_in[0];
    const float* z     = (const float*)d_in[1];
    const float* rots  = (const float*)d_in[2];
    const float* trans = (const float*)d_in[3];
    const float* mask  = (const float*)d_in[4];
    const float* Wq    = (const float*)d_in[5];
    const float* bq    = (const float*)d_in[6];
    const float* Wkv   = (const float*)d_in[7];
    const float* bkv   = (const float*)d_in[8];
    const float* Wq3   = (const float*)d_in[9];
    const float* bq3   = (const float*)d_in[10];
    const float* Wkv3  = (const float*)d_in[11];
    const float* bkv3  = (const float*)d_in[12];
    const float* Wb    = (const float*)d_in[13];
    const float* bb    = (const float*)d_in[14];
    const float* hw    = (const float*)d_in[15];
    const float* Wo    = (const float*)d_in[16];
    const float* bo    = (const float*)d_in[17];
    float* out = (float*)d_out;

    char* ws = (char*)d_ws;
    float*          Qw   = (float*)(ws + 0);              // 589824 B
    float*          Q3w  = (float*)(ws + 589824);         // 442368 B
    unsigned short* Kw   = (unsigned short*)(ws + 1032192);  // 294912 B
    unsigned short* Vt   = (unsigned short*)(ws + 1327104);  // 294912 B
    float*          K3w  = (float*)(ws + 1622016);        // 442368 B
    unsigned short* V3t  = (unsigned short*)(ws + 2064384);  // 442368 B
    float*          P3q  = (float*)(ws + 2506752);        // 442368 B
    float*          P3kv = (float*)(ws + 2949120);        // 1327104 B
    unsigned short* EQw  = (unsigned short*)(ws + 4276224);  // 589824 B
    unsigned short* EKw  = (unsigned short*)(ws + 4866048);  // 589824 B
    unsigned short* OF   = (unsigned short*)(ws + 5455872);  // 3244032 B
    float*          part3 = (float*)(ws + 8699904);       // 15728640 B
    float*          part  = (float*)(ws + 8699904);       // shared (disjoint lifetime)

    proj_kernel<<<dim3(24, 9), 256, 0, stream>>>(
        s, Wq, bq, Wkv, bkv, Wq3, bq3, Wkv3, bkv3, Qw, Kw, Vt, P3q, P3kv);
    rot3_kernel<<<768, 192, 0, stream>>>(P3q, P3kv, rots, trans, Q3w, K3w, V3t);
    ek_kernel<<<192, 256, 0, stream>>>(Qw, Kw, Q3w, K3w, mask, hw, bb, EQw, EKw);
    ipa_main<<<1536, 256, 0, stream>>>(z, Wb, EQw, EKw, Vt, V3t, part3);
    combine_kernel<<<768, 256, 0, stream>>>(part3, rots, trans, OF);
    out_gemm<<<dim3(6, 6, 6), 256, 0, stream>>>(OF, Wo, part);
    reduce_out<<<1152, 256, 0, stream>>>(part, bo, out);
}